// Round 3
// baseline (223.972 us; speedup 1.0000x reference)
//
#include <hip/hip_runtime.h>
#include <cstdint>
#include <cstddef>

// CPDLoss (SSD MultiBox-style): B=8, A=131072, M=64.
// R3: 4 dispatches: memset -> k_match (fused prep, compacted truths, 4 waves/SIMD)
//     -> k_main (fused override via LDS scatter table, builds level-1 hist)
//     -> k_select (fused 3-level radix select + final output, 1 block/batch).

#define A_N 131072
#define B_N 8
#define M_N 64
#define OVTH 0.5f
#define VAR0 0.1f

// ---------------------------------------------------------------- match kernel
// 512 thr/block, 4 anchors/thread (i*512 stride), grid (64, 8).
// Prep fused: wave 0 loads targets, computes area/validity, compacts valid
// truths (ballot prefix) into LDS in ascending-m order -> branch-free loop.
// Per valid truth: 4 IoU (exact IEEE div), per-anchor (bv,bm) strict-> update
// (= np first-max over m), ONE u64 key butterfly (q_bits<<32 | (0x7FFFFFFF-a):
// tie -> smallest anchor = np first-max over anchors), wave winners -> LDS ->
// global atomicMax(bpi). Output (ov,idx) packed u64.
__launch_bounds__(512)
__global__ void k_match(const float4* __restrict__ anchors,
                        const float*  __restrict__ targets,
                        unsigned long long* __restrict__ ovIdx,
                        unsigned long long* __restrict__ bpi)
{
  __shared__ float4 sBX[M_N];
  __shared__ float  sBA[M_N];
  __shared__ int    sBM[M_N];
  __shared__ int    sNV;
  __shared__ unsigned long long sKey[M_N][8];
  const int tid = threadIdx.x;
  const int wave = tid >> 6, lane = tid & 63;
  const int b = blockIdx.y;
  sKey[tid >> 3][tid & 7] = 0ull;
  if (tid < M_N) {
    const float* t = targets + ((size_t)b * M_N + tid) * 5;
    float x1 = t[0], y1 = t[1], x2 = t[2], y2 = t[3], lab = t[4];
    bool valid = lab > 0.f;
    unsigned long long mask = __ballot(valid);
    int pfx = __popcll(mask & ((1ull << tid) - 1ull));
    if (valid) {
      sBX[pfx] = make_float4(x1, y1, x2, y2);
      sBA[pfx] = (x2 - x1) * (y2 - y1);
      sBM[pfx] = tid;
    }
    if (tid == 0) sNV = (int)__popcll(mask);
  }
  __syncthreads();
  const int nv = sNV;
  const int a0 = blockIdx.x * 2048 + tid;
  float ax1[4], ay1[4], ax2[4], ay2[4], sa[4];
  unsigned int inv[4];
  float bv[4]; int bm[4];
  #pragma unroll
  for (int i = 0; i < 4; ++i) {
    float4 an = anchors[a0 + i * 512];
    ax1[i] = an.x - an.z * 0.5f; ay1[i] = an.y - an.w * 0.5f;
    ax2[i] = an.x + an.z * 0.5f; ay2[i] = an.y + an.w * 0.5f;
    sa[i] = (ax2[i] - ax1[i]) * (ay2[i] - ay1[i]);
    inv[i] = 0x7FFFFFFFu - (unsigned)(a0 + i * 512);
    bv[i] = -1.0f; bm[i] = 0;   // invalid rows (-1) can never beat a valid q>=0;
  }                              // all-invalid edge: ov=-1, idx=0 == np.argmax
  #pragma unroll 2
  for (int j = 0; j < nv; ++j) {
    float4 t = sBX[j];
    float ta = sBA[j];
    int mm = sBM[j];
    unsigned long long key = 0ull;
    #pragma unroll
    for (int i = 0; i < 4; ++i) {
      float wx = fminf(ax2[i], t.z) - fmaxf(ax1[i], t.x);
      float wy = fminf(ay2[i], t.w) - fmaxf(ay1[i], t.y);
      float inter = fmaxf(wx, 0.f) * fmaxf(wy, 0.f);
      float uni = (sa[i] + ta) - inter;
      float q = inter / uni;                  // exact IEEE div: np ordering
      if (q > bv[i]) { bv[i] = q; bm[i] = mm; }
      unsigned long long k2 =
          ((unsigned long long)__float_as_uint(q) << 32) | inv[i];
      key = (k2 > key) ? k2 : key;
    }
    #pragma unroll
    for (int off = 32; off; off >>= 1) {
      unsigned long long o = __shfl_xor(key, off);
      key = (o > key) ? o : key;
    }
    if (lane == 0) sKey[mm][wave] = key;
  }
  #pragma unroll
  for (int i = 0; i < 4; ++i) {
    ovIdx[(size_t)b * A_N + a0 + i * 512] =
        ((unsigned long long)__float_as_uint(bv[i]) << 32) | (unsigned)bm[i];
  }
  __syncthreads();
  if (tid < M_N) {
    unsigned long long k0 = sKey[tid][0];
    #pragma unroll
    for (int w = 1; w < 8; ++w) {
      unsigned long long k2 = sKey[tid][w];
      k0 = (k2 > k0) ? k2 : k0;
    }
    if (k0) atomicMax(bpi + b * M_N + tid, k0);
  }
}

// ------------------------------------------------------------------- main pass
// Fused override: per-block LDS table[4096], atomicMax by m (last-write-wins ==
// max m for duplicate anchors, = numpy sequential scatter). Builds level-1
// histogram (top-11 bits of CE float) + loc loss + pos CE + numpos.
__launch_bounds__(256)
__global__ void k_main(const float2* __restrict__ loc_pred,
                       const float2* __restrict__ conf_pred,
                       const float4* __restrict__ anchors,
                       const float*  __restrict__ targets,
                       const unsigned long long* __restrict__ bpi,
                       const unsigned long long* __restrict__ ovIdx,
                       unsigned int* __restrict__ ceBits,
                       unsigned int* __restrict__ h1cnt,
                       double* __restrict__ h1sum,
                       double* __restrict__ lossL,
                       double* __restrict__ lossCpos,
                       unsigned int* __restrict__ numpos)
{
  __shared__ int   ovTab[4096];
  __shared__ unsigned int hc[2048];
  __shared__ float hs[2048];
  __shared__ float4 sBX[M_N];
  __shared__ unsigned char sVal[M_N];
  __shared__ double rL[4], rC[4];
  __shared__ unsigned int rN[4];
  const int tid = threadIdx.x;
  const int b = blockIdx.y;
  const int base = blockIdx.x * 4096;
  for (int j = tid; j < 4096; j += 256) ovTab[j] = -1;
  for (int j = tid; j < 2048; j += 256) { hc[j] = 0u; hs[j] = 0.f; }
  if (tid < M_N) {
    const float* t = targets + ((size_t)b * M_N + tid) * 5;
    sBX[tid] = make_float4(t[0], t[1], t[2], t[3]);
    sVal[tid] = t[4] > 0.f ? 1 : 0;
  }
  __syncthreads();
  if (tid < M_N && sVal[tid]) {
    unsigned long long key = bpi[b * M_N + tid];
    int a = (int)(0x7FFFFFFFu - (unsigned)(key & 0xFFFFFFFFull));
    int loc = a - base;
    if (loc >= 0 && loc < 4096) atomicMax(&ovTab[loc], tid);
  }
  __syncthreads();
  double lL = 0.0, lC = 0.0;
  unsigned int npc = 0;
  for (int i = 0; i < 16; ++i) {
    const int local = i * 256 + tid;
    const int a = base + local;
    const size_t g = (size_t)b * A_N + a;
    unsigned long long oi = ovIdx[g];
    float ov = __uint_as_float((unsigned)(oi >> 32));
    int idx = (int)(oi & 0xFFFFFFFFull);
    int movr = ovTab[local];
    if (movr >= 0) { ov = 2.0f; idx = movr; }
    int conf = (ov < OVTH) ? 0 : (sVal[idx] ? 1 : 0);
    float2 cp = conf_pred[g];
    float mx = fmaxf(cp.x, cp.y), mn = fminf(cp.x, cp.y);
    float ce = (mx + log1pf(expf(mn - mx))) - (conf ? cp.y : cp.x);
    unsigned int bits = 0u;
    float hval = 0.f;
    if (conf) {
      npc++; lC += (double)ce;
      float4 t = sBX[idx];
      float4 an = anchors[a];
      float gx = ((t.x + t.z) * 0.5f - an.x) / (VAR0 * an.z);
      float gy = ((t.y + t.w) * 0.5f - an.y) / (VAR0 * an.w);
      float2 lp = loc_pred[g];
      float dx = fabsf(lp.x - gx), dy = fabsf(lp.y - gy);
      lL += (double)((dx < 1.f ? 0.5f * dx * dx : dx - 0.5f) +
                     (dy < 1.f ? 0.5f * dy * dy : dy - 0.5f));
    } else {
      bits = __float_as_uint(ce);   // ce > 0 -> monotone bits
      hval = ce;
    }
    ceBits[g] = bits;
    atomicAdd(&hc[bits >> 21], 1u);
    atomicAdd(&hs[bits >> 21], hval);
  }
  __syncthreads();
  for (int j = tid; j < 2048; j += 256) {
    unsigned int c = hc[j];
    if (c) {
      atomicAdd(h1cnt + b * 2048 + j, c);
      atomicAdd(h1sum + b * 2048 + j, (double)hs[j]);
    }
  }
  const int lane = tid & 63, wave = tid >> 6;
  for (int off = 32; off; off >>= 1) {
    lL += __shfl_down(lL, off);
    lC += __shfl_down(lC, off);
    npc += __shfl_down(npc, off);
  }
  if (lane == 0) { rL[wave] = lL; rC[wave] = lC; rN[wave] = npc; }
  __syncthreads();
  if (tid == 0) {
    double aL = 0, aC = 0; unsigned int n = 0;
    for (int w = 0; w < 4; ++w) { aL += rL[w]; aC += rC[w]; n += rN[w]; }
    if (aL != 0.0) atomicAdd(lossL, aL);
    if (aC != 0.0) atomicAdd(lossCpos, aC);
    if (n) atomicAdd(numpos + b, n);
  }
}

// ------------------------------------------------- radix-select helper (block)
template <int PER>
__device__ void findBin(const unsigned int* h, unsigned int k,
                        unsigned int* scanBuf, int* outT, unsigned int* outAb)
{
  const int tid = threadIdx.x;
  unsigned int c[PER];
  unsigned int ps = 0;
  #pragma unroll
  for (int j = 0; j < PER; ++j) { c[j] = h[tid * PER + j]; ps += c[j]; }
  scanBuf[tid] = ps;
  __syncthreads();
  unsigned int v = ps;
  for (int off = 1; off < 256; off <<= 1) {
    unsigned int u = (tid + off < 256) ? scanBuf[tid + off] : 0u;
    __syncthreads();
    v += u;
    scanBuf[tid] = v;
    __syncthreads();
  }
  unsigned int above = v - ps;
  #pragma unroll
  for (int j = PER - 1; j >= 0; --j) {
    unsigned int cj = c[j];
    if (above < k && above + cj >= k) { *outT = tid * PER + j; *outAb = above; }
    above += cj;
  }
  __syncthreads();
}

// -------------------------------------------------- selection + final combine
// 1 block per batch. Level 2/3 histograms in LDS; two uint4 passes over the
// batch's ceBits (512 KB each, L2-resident). Exact: 11+11+10 = 32 bits fully
// determine the boundary value.
__launch_bounds__(256)
__global__ void k_select(const unsigned int* __restrict__ ceBits,
                         const unsigned int* __restrict__ h1cnt,
                         const double* __restrict__ h1sum,
                         const unsigned int* __restrict__ numpos,
                         const double* __restrict__ lossL,
                         const double* __restrict__ lossCpos,
                         double* __restrict__ lossCneg,
                         unsigned int* __restrict__ ticket,
                         float* __restrict__ out)
{
  __shared__ unsigned int scanBuf[256];
  __shared__ int sT; __shared__ unsigned int sAb;
  __shared__ unsigned int h2c[2048];
  __shared__ float h2s[2048];
  __shared__ unsigned int h3c[1024];
  __shared__ double lred[4];
  const int b = blockIdx.x;
  const int tid = threadIdx.x;
  const unsigned int P = numpos[b];
  const unsigned int k = min(3u * P, (unsigned)A_N - P);
  if (k > 0u) {
    findBin<8>(h1cnt + b * 2048, k, scanBuf, &sT, &sAb);
    const int t1 = sT; const unsigned int k1 = k - sAb;
    for (int j = tid; j < 2048; j += 256) { h2c[j] = 0u; h2s[j] = 0.f; }
    for (int j = tid; j < 1024; j += 256) h3c[j] = 0u;
    __syncthreads();
    const uint4* cb = (const uint4*)(ceBits + (size_t)b * A_N);
    for (int i = 0; i < 128; ++i) {
      uint4 v = cb[i * 256 + tid];
      unsigned int xs[4] = {v.x, v.y, v.z, v.w};
      #pragma unroll
      for (int c = 0; c < 4; ++c) {
        unsigned int x = xs[c];
        if ((int)(x >> 21) == t1) {
          atomicAdd(&h2c[(x >> 10) & 2047], 1u);
          atomicAdd(&h2s[(x >> 10) & 2047], __uint_as_float(x));
        }
      }
    }
    __syncthreads();
    findBin<8>(h2c, k1, scanBuf, &sT, &sAb);
    const int t2 = sT; const unsigned int k2 = k1 - sAb;
    const unsigned int pfx = (((unsigned)t1 << 11) | (unsigned)t2);
    for (int i = 0; i < 128; ++i) {
      uint4 v = cb[i * 256 + tid];
      unsigned int xs[4] = {v.x, v.y, v.z, v.w};
      #pragma unroll
      for (int c = 0; c < 4; ++c) {
        unsigned int x = xs[c];
        if ((x >> 10) == pfx) atomicAdd(&h3c[x & 1023], 1u);
      }
    }
    __syncthreads();
    findBin<4>(h3c, k2, scanBuf, &sT, &sAb);
    const int t3 = sT; const unsigned int ab3 = sAb;
    double s = 0.0;
    for (int j = tid; j < 2048; j += 256) {
      if (j > t1) s += h1sum[b * 2048 + j];
      if (j > t2) s += (double)h2s[j];
    }
    for (int j = tid; j < 1024; j += 256) {
      if (j > t3) {
        unsigned int cc = h3c[j];
        if (cc) s += (double)cc * (double)__uint_as_float(
                     (((unsigned)t1 << 21) | ((unsigned)t2 << 10) | (unsigned)j));
      }
    }
    const int lane = tid & 63, wave = tid >> 6;
    for (int off = 32; off; off >>= 1) s += __shfl_down(s, off);
    if (lane == 0) lred[wave] = s;
    __syncthreads();
    if (tid == 0) {
      double tot = lred[0] + lred[1] + lred[2] + lred[3];
      tot += (double)(k2 - ab3) * (double)__uint_as_float(
                 (((unsigned)t1 << 21) | ((unsigned)t2 << 10) | (unsigned)t3));
      atomicAdd(lossCneg, tot);
    }
  }
  __threadfence();
  if (tid == 0) {
    unsigned int tk = atomicAdd(ticket, 1u);
    if (tk == B_N - 1) {
      double lcn = atomicAdd(lossCneg, 0.0);
      double ll = *lossL, lcp = *lossCpos;
      unsigned int tot = 0;
      #pragma unroll
      for (int i = 0; i < B_N; ++i) tot += numpos[i];
      double tn = (double)tot;
      out[0] = (float)(ll / tn);
      out[1] = (float)((lcp + lcn) / tn);
    }
  }
}

// -------------------------------------------------------------------- launcher
extern "C" void kernel_launch(void* const* d_in, const int* in_sizes, int n_in,
                              void* d_out, int out_size, void* d_ws, size_t ws_size,
                              hipStream_t stream)
{
  const float2* loc     = (const float2*)d_in[0];  // (B,A,2)
  const float2* confp   = (const float2*)d_in[1];  // (B,A,2)
  const float4* anchors = (const float4*)d_in[2];  // (A,4)
  const float*  targets = (const float*)d_in[3];   // (B,M,5)
  char* ws = (char*)d_ws;
  // zero-init region [0, 200768): scalars, bpi, h1 counts, h1 sums
  double* lossL  = (double*)(ws + 0);
  double* lossCp = (double*)(ws + 8);
  double* lossCn = (double*)(ws + 16);
  unsigned int* ticket = (unsigned int*)(ws + 24);
  unsigned int* numpos = (unsigned int*)(ws + 32);          // [8]
  unsigned long long* bpi = (unsigned long long*)(ws + 64); // [512]
  unsigned int* h1c = (unsigned int*)(ws + 4160);           // [8*2048]
  double* h1s = (double*)(ws + 69696);                      // [8*2048]
  const size_t ZINIT = 200768;
  unsigned long long* ovIdx = (unsigned long long*)(ws + ZINIT);        // [B*A]
  unsigned int* ceBits = (unsigned int*)(ws + ZINIT + 8388608);         // [B*A]
  // total ws use ~12.8 MB

  hipMemsetAsync(d_ws, 0, ZINIT, stream);
  k_match<<<dim3(64, 8), 512, 0, stream>>>(anchors, targets, ovIdx, bpi);
  k_main<<<dim3(32, 8), 256, 0, stream>>>(loc, confp, anchors, targets, bpi,
                                          ovIdx, ceBits, h1c, h1s, lossL, lossCp,
                                          numpos);
  k_select<<<8, 256, 0, stream>>>(ceBits, h1c, h1s, numpos, lossL, lossCp,
                                  lossCn, ticket, (float*)d_out);
}

// Round 4
// 141.067 us; speedup vs baseline: 1.5877x; 1.5877x over previous
//
#include <hip/hip_runtime.h>
#include <cstdint>
#include <cstddef>

// CPDLoss (SSD MultiBox-style): B=8, A=131072, M=64.
// R4: memset -> k_match (u8 out, rcp IoU, f32 butterfly) -> k_main (LDS-packed
// u64 histogram) -> k_sel2 (32,8) -> k_sel3 (32,8) -> k_final (8 blocks, bins
// only). Histograms pack cnt<<46 | fixed-point(ce * 2^20) in one u64.

#define A_N 131072
#define B_N 8
#define M_N 64
#define OVTH 0.5f
#define VAR0 0.1f
#define CNT_SH 46
#define SUM_MASK ((1ull << CNT_SH) - 1ull)
#define FIXF 1048576.0f
#define INV_FIX (1.0 / 1048576.0)

static __device__ __forceinline__ unsigned long long packCE(float ce) {
  return (1ull << CNT_SH) | (unsigned long long)(ce * FIXF + 0.5f);
}

// ---------------------------------------------------------------- match kernel
// 512 thr/block, 4 anchors/thread (stride 512), grid (64,8). Targets compacted
// (ballot prefix) -> branch-free valid-truth loop. Per truth: 4 IoU via
// v_rcp_f32, per-anchor strict-> (np first-max), f32 max butterfly + ballot
// lowest-lane tie, per-wave packed u64 key -> LDS -> global atomicMax(bpi).
// Output u8: bit7 = (best_ov >= 0.5), bits0-5 = best_truth_idx.
__launch_bounds__(512)
__global__ void k_match(const float4* __restrict__ anchors,
                        const float*  __restrict__ targets,
                        unsigned char* __restrict__ matchOut,
                        unsigned long long* __restrict__ bpi)
{
  __shared__ float4 sBX[M_N];
  __shared__ float  sBA[M_N];
  __shared__ int    sBM[M_N];
  __shared__ int    sNV;
  __shared__ unsigned long long sKey[M_N][8];
  const int tid = threadIdx.x;
  const int wave = tid >> 6, lane = tid & 63;
  const int b = blockIdx.y;
  sKey[tid >> 3][tid & 7] = 0ull;
  if (tid < M_N) {
    const float* t = targets + ((size_t)b * M_N + tid) * 5;
    float x1 = t[0], y1 = t[1], x2 = t[2], y2 = t[3], lab = t[4];
    bool valid = lab > 0.f;
    unsigned long long mask = __ballot(valid);
    int pfx = __popcll(mask & ((1ull << tid) - 1ull));
    if (valid) {
      sBX[pfx] = make_float4(x1, y1, x2, y2);
      sBA[pfx] = (x2 - x1) * (y2 - y1);
      sBM[pfx] = tid;
    }
    if (tid == 0) sNV = (int)__popcll(mask);
  }
  __syncthreads();
  const int nv = sNV;
  const int a0 = blockIdx.x * 2048 + tid;
  float ax1[4], ay1[4], ax2[4], ay2[4], sa[4];
  float bv[4]; int bm[4];
  #pragma unroll
  for (int i = 0; i < 4; ++i) {
    float4 an = anchors[a0 + i * 512];
    ax1[i] = an.x - an.z * 0.5f; ay1[i] = an.y - an.w * 0.5f;
    ax2[i] = an.x + an.z * 0.5f; ay2[i] = an.y + an.w * 0.5f;
    sa[i] = (ax2[i] - ax1[i]) * (ay2[i] - ay1[i]);
    bv[i] = -1.0f; bm[i] = 0;
  }
  #pragma unroll 2
  for (int j = 0; j < nv; ++j) {
    float4 t = sBX[j];
    float ta = sBA[j];
    int mm = sBM[j];
    float lb = -1.0f; int li = 0;
    #pragma unroll
    for (int i = 0; i < 4; ++i) {
      float wx = fminf(ax2[i], t.z) - fmaxf(ax1[i], t.x);
      float wy = fminf(ay2[i], t.w) - fmaxf(ay1[i], t.y);
      float inter = fmaxf(wx, 0.f) * fmaxf(wy, 0.f);
      float uni = (sa[i] + ta) - inter;
      float q = inter * __builtin_amdgcn_rcpf(uni);
      if (q > bv[i]) { bv[i] = q; bm[i] = mm; }
      if (q > lb) { lb = q; li = i; }
    }
    float wm = lb;
    #pragma unroll
    for (int off = 32; off; off >>= 1) wm = fmaxf(wm, __shfl_xor(wm, off));
    unsigned long long msk = __ballot(lb == wm);
    int lead = __ffsll((unsigned long long)msk) - 1;
    int wi = __shfl(li, lead);
    if (lane == 0) {
      int aw = blockIdx.x * 2048 + wave * 64 + lead + wi * 512;
      sKey[mm][wave] = ((unsigned long long)__float_as_uint(wm) << 32) |
                       (unsigned long long)(0x7FFFFFFFu - (unsigned)aw);
    }
  }
  #pragma unroll
  for (int i = 0; i < 4; ++i) {
    matchOut[(size_t)b * A_N + a0 + i * 512] =
        (unsigned char)(((bv[i] >= OVTH) ? 0x80 : 0) | bm[i]);
  }
  __syncthreads();
  if (tid < M_N) {
    unsigned long long k0 = sKey[tid][0];
    #pragma unroll
    for (int w = 1; w < 8; ++w) {
      unsigned long long k2 = sKey[tid][w];
      k0 = (k2 > k0) ? k2 : k0;
    }
    if (k0) atomicMax(bpi + b * M_N + tid, k0);
  }
}

// ------------------------------------------------------------------- main pass
// Fused override (LDS scatter, atomicMax by m = last-write-wins), CE, smooth-L1
// for positives, level-1 histogram (bits>>21) as packed u64 in LDS -> global.
__launch_bounds__(256)
__global__ void k_main(const float2* __restrict__ loc_pred,
                       const float2* __restrict__ conf_pred,
                       const float4* __restrict__ anchors,
                       const float*  __restrict__ targets,
                       const unsigned long long* __restrict__ bpi,
                       const unsigned char* __restrict__ matchOut,
                       unsigned int* __restrict__ ceBits,
                       unsigned long long* __restrict__ h1,
                       double* __restrict__ lossL,
                       double* __restrict__ lossCpos,
                       unsigned int* __restrict__ numpos)
{
  __shared__ int ovTab[4096];
  __shared__ unsigned long long hh[2048];
  __shared__ float4 sBX[M_N];
  __shared__ double rL[4], rC[4];
  __shared__ unsigned int rN[4];
  const int tid = threadIdx.x;
  const int b = blockIdx.y;
  const int base = blockIdx.x * 4096;
  for (int j = tid; j < 4096; j += 256) ovTab[j] = -1;
  for (int j = tid; j < 2048; j += 256) hh[j] = 0ull;
  if (tid < M_N) {
    const float* t = targets + ((size_t)b * M_N + tid) * 5;
    sBX[tid] = make_float4(t[0], t[1], t[2], t[3]);
  }
  __syncthreads();
  if (tid < M_N) {
    unsigned long long key = bpi[b * M_N + tid];
    if (key) {
      int a = (int)(0x7FFFFFFFu - (unsigned)(key & 0xFFFFFFFFull));
      int loc = a - base;
      if (loc >= 0 && loc < 4096) atomicMax(&ovTab[loc], tid);
    }
  }
  __syncthreads();
  double lL = 0.0, lC = 0.0;
  unsigned int npc = 0;
  for (int i = 0; i < 16; ++i) {
    const int local = i * 256 + tid;
    const int a = base + local;
    const size_t g = (size_t)b * A_N + a;
    unsigned char mb = matchOut[g];
    int movr = ovTab[local];
    bool conf = (mb & 0x80) || (movr >= 0);
    int idx = (movr >= 0) ? movr : (mb & 63);
    float2 cp = conf_pred[g];
    float mx = fmaxf(cp.x, cp.y), mn = fminf(cp.x, cp.y);
    float ce = (mx + log1pf(expf(mn - mx))) - (conf ? cp.y : cp.x);
    unsigned int bits = 0u;
    if (conf) {
      npc++; lC += (double)ce;
      float4 t = sBX[idx];
      float4 an = anchors[a];
      float gx = ((t.x + t.z) * 0.5f - an.x) / (VAR0 * an.z);
      float gy = ((t.y + t.w) * 0.5f - an.y) / (VAR0 * an.w);
      float2 lp = loc_pred[g];
      float dx = fabsf(lp.x - gx), dy = fabsf(lp.y - gy);
      lL += (double)((dx < 1.f ? 0.5f * dx * dx : dx - 0.5f) +
                     (dy < 1.f ? 0.5f * dy * dy : dy - 0.5f));
    } else {
      bits = __float_as_uint(ce);   // ce >= 0 -> monotone bits, bit31 == 0
      atomicAdd(&hh[bits >> 21], packCE(ce));
    }
    ceBits[g] = bits;
  }
  __syncthreads();
  for (int j = tid; j < 2048; j += 256) {
    unsigned long long v = hh[j];
    if (v) atomicAdd(&h1[(size_t)b * 2048 + j], v);
  }
  const int lane = tid & 63, wave = tid >> 6;
  for (int off = 32; off; off >>= 1) {
    lL += __shfl_down(lL, off);
    lC += __shfl_down(lC, off);
    npc += __shfl_down(npc, off);
  }
  if (lane == 0) { rL[wave] = lL; rC[wave] = lC; rN[wave] = npc; }
  __syncthreads();
  if (tid == 0) {
    double aL = 0, aC = 0; unsigned int n = 0;
    for (int w = 0; w < 4; ++w) { aL += rL[w]; aC += rC[w]; n += rN[w]; }
    if (aL != 0.0) atomicAdd(lossL, aL);
    if (aC != 0.0) atomicAdd(lossCpos, aC);
    if (n) atomicAdd(numpos + b, n);
  }
}

// ---------------------------------------- radix-select helpers (block-uniform)
// Find bin t containing the k-th largest; outAb = count strictly above t.
template <int PER>
__device__ void findBinP(const unsigned long long* __restrict__ h, unsigned int k,
                         unsigned int* scanBuf, int* outT, unsigned int* outAb)
{
  const int tid = threadIdx.x;
  unsigned int c[PER];
  unsigned int ps = 0;
  #pragma unroll
  for (int j = 0; j < PER; ++j) {
    c[j] = (unsigned int)(h[tid * PER + j] >> CNT_SH);
    ps += c[j];
  }
  scanBuf[tid] = ps;
  __syncthreads();
  unsigned int v = ps;
  for (int off = 1; off < 256; off <<= 1) {
    unsigned int u = (tid + off < 256) ? scanBuf[tid + off] : 0u;
    __syncthreads();
    v += u;
    scanBuf[tid] = v;
    __syncthreads();
  }
  unsigned int above = v - ps;
  #pragma unroll
  for (int j = PER - 1; j >= 0; --j) {
    unsigned int cj = c[j];
    if (above < k && above + cj >= k) { *outT = tid * PER + j; *outAb = above; }
    above += cj;
  }
  __syncthreads();
}

template <int PER>
__device__ void findBinU(const unsigned int* __restrict__ h, unsigned int k,
                         unsigned int* scanBuf, int* outT, unsigned int* outAb)
{
  const int tid = threadIdx.x;
  unsigned int c[PER];
  unsigned int ps = 0;
  #pragma unroll
  for (int j = 0; j < PER; ++j) { c[j] = h[tid * PER + j]; ps += c[j]; }
  scanBuf[tid] = ps;
  __syncthreads();
  unsigned int v = ps;
  for (int off = 1; off < 256; off <<= 1) {
    unsigned int u = (tid + off < 256) ? scanBuf[tid + off] : 0u;
    __syncthreads();
    v += u;
    scanBuf[tid] = v;
    __syncthreads();
  }
  unsigned int above = v - ps;
  #pragma unroll
  for (int j = PER - 1; j >= 0; --j) {
    unsigned int cj = c[j];
    if (above < k && above + cj >= k) { *outT = tid * PER + j; *outAb = above; }
    above += cj;
  }
  __syncthreads();
}

// ----------------------------------------------------------- level-2 histogram
__launch_bounds__(256)
__global__ void k_sel2(const unsigned int* __restrict__ ceBits,
                       const unsigned long long* __restrict__ h1,
                       unsigned long long* __restrict__ h2,
                       const unsigned int* __restrict__ numpos)
{
  __shared__ unsigned int scanBuf[256];
  __shared__ int sT; __shared__ unsigned int sAb;
  __shared__ unsigned long long hh[2048];
  const int b = blockIdx.y;
  const unsigned int P = numpos[b];
  const unsigned int k = min(3u * P, (unsigned)A_N - P);
  if (k == 0u) return;
  const int tid = threadIdx.x;
  findBinP<8>(h1 + (size_t)b * 2048, k, scanBuf, &sT, &sAb);
  const int t1 = sT;
  for (int j = tid; j < 2048; j += 256) hh[j] = 0ull;
  __syncthreads();
  const uint4* cb = (const uint4*)(ceBits + (size_t)b * A_N + blockIdx.x * 4096);
  for (int i = 0; i < 4; ++i) {
    uint4 v = cb[i * 256 + tid];
    unsigned int xs[4] = {v.x, v.y, v.z, v.w};
    #pragma unroll
    for (int c = 0; c < 4; ++c) {
      unsigned int x = xs[c];
      if (x && (int)(x >> 21) == t1)
        atomicAdd(&hh[(x >> 10) & 2047], packCE(__uint_as_float(x)));
    }
  }
  __syncthreads();
  for (int j = tid; j < 2048; j += 256) {
    unsigned long long v = hh[j];
    if (v) atomicAdd(&h2[(size_t)b * 2048 + j], v);
  }
}

// ----------------------------------------------------------- level-3 histogram
__launch_bounds__(256)
__global__ void k_sel3(const unsigned int* __restrict__ ceBits,
                       const unsigned long long* __restrict__ h1,
                       const unsigned long long* __restrict__ h2,
                       unsigned int* __restrict__ h3,
                       const unsigned int* __restrict__ numpos)
{
  __shared__ unsigned int scanBuf[256];
  __shared__ int sT; __shared__ unsigned int sAb;
  __shared__ unsigned int hh[1024];
  const int b = blockIdx.y;
  const unsigned int P = numpos[b];
  const unsigned int k = min(3u * P, (unsigned)A_N - P);
  if (k == 0u) return;
  const int tid = threadIdx.x;
  findBinP<8>(h1 + (size_t)b * 2048, k, scanBuf, &sT, &sAb);
  const int t1 = sT; const unsigned int k1 = k - sAb;
  findBinP<8>(h2 + (size_t)b * 2048, k1, scanBuf, &sT, &sAb);
  const int t2 = sT;
  const unsigned int pfx = (((unsigned)t1 << 11) | (unsigned)t2);
  for (int j = tid; j < 1024; j += 256) hh[j] = 0u;
  __syncthreads();
  const uint4* cb = (const uint4*)(ceBits + (size_t)b * A_N + blockIdx.x * 4096);
  for (int i = 0; i < 4; ++i) {
    uint4 v = cb[i * 256 + tid];
    unsigned int xs[4] = {v.x, v.y, v.z, v.w};
    #pragma unroll
    for (int c = 0; c < 4; ++c) {
      unsigned int x = xs[c];
      if ((x >> 10) == pfx) atomicAdd(&hh[x & 1023], 1u);
    }
  }
  __syncthreads();
  for (int j = tid; j < 1024; j += 256) {
    unsigned int v = hh[j];
    if (v) atomicAdd(&h3[(size_t)b * 1024 + j], v);
  }
}

// --------------------------------------------------------------- final combine
// 8 blocks; scans only histogram bins (2048+2048+1024), no ceBits pass.
__launch_bounds__(256)
__global__ void k_final(const unsigned long long* __restrict__ h1,
                        const unsigned long long* __restrict__ h2,
                        const unsigned int* __restrict__ h3,
                        const unsigned int* __restrict__ numpos,
                        const double* __restrict__ lossL,
                        const double* __restrict__ lossCpos,
                        double* __restrict__ lossCneg,
                        unsigned int* __restrict__ ticket,
                        float* __restrict__ out)
{
  __shared__ unsigned int scanBuf[256];
  __shared__ int sT; __shared__ unsigned int sAb;
  __shared__ double lred[4];
  const int b = blockIdx.x;
  const int tid = threadIdx.x;
  const unsigned int P = numpos[b];
  const unsigned int k = min(3u * P, (unsigned)A_N - P);
  if (k > 0u) {
    findBinP<8>(h1 + (size_t)b * 2048, k, scanBuf, &sT, &sAb);
    const int t1 = sT; const unsigned int k1 = k - sAb;
    findBinP<8>(h2 + (size_t)b * 2048, k1, scanBuf, &sT, &sAb);
    const int t2 = sT; const unsigned int k2 = k1 - sAb;
    findBinU<4>(h3 + (size_t)b * 1024, k2, scanBuf, &sT, &sAb);
    const int t3 = sT; const unsigned int ab3 = sAb;
    double sfix = 0.0, sval = 0.0;
    for (int j = tid; j < 2048; j += 256) {
      if (j > t1) sfix += (double)(h1[(size_t)b * 2048 + j] & SUM_MASK);
      if (j > t2) sfix += (double)(h2[(size_t)b * 2048 + j] & SUM_MASK);
    }
    for (int j = tid; j < 1024; j += 256) {
      if (j > t3) {
        unsigned int cc = h3[(size_t)b * 1024 + j];
        if (cc) sval += (double)cc * (double)__uint_as_float(
                     (((unsigned)t1 << 21) | ((unsigned)t2 << 10) | (unsigned)j));
      }
    }
    double s = sfix * INV_FIX + sval;
    const int lane = tid & 63, wave = tid >> 6;
    for (int off = 32; off; off >>= 1) s += __shfl_down(s, off);
    if (lane == 0) lred[wave] = s;
    __syncthreads();
    if (tid == 0) {
      double tot = lred[0] + lred[1] + lred[2] + lred[3];
      tot += (double)(k2 - ab3) * (double)__uint_as_float(
                 (((unsigned)t1 << 21) | ((unsigned)t2 << 10) | (unsigned)t3));
      atomicAdd(lossCneg, tot);
    }
  }
  __threadfence();
  if (tid == 0) {
    unsigned int tk = atomicAdd(ticket, 1u);
    if (tk == B_N - 1) {
      double lcn = atomicAdd(lossCneg, 0.0);
      double ll = *lossL, lcp = *lossCpos;
      unsigned int tot = 0;
      #pragma unroll
      for (int i = 0; i < B_N; ++i) tot += numpos[i];
      double tn = (double)tot;
      out[0] = (float)(ll / tn);
      out[1] = (float)((lcp + lcn) / tn);
    }
  }
}

// -------------------------------------------------------------------- launcher
extern "C" void kernel_launch(void* const* d_in, const int* in_sizes, int n_in,
                              void* d_out, int out_size, void* d_ws, size_t ws_size,
                              hipStream_t stream)
{
  const float2* loc     = (const float2*)d_in[0];  // (B,A,2)
  const float2* confp   = (const float2*)d_in[1];  // (B,A,2)
  const float4* anchors = (const float4*)d_in[2];  // (A,4)
  const float*  targets = (const float*)d_in[3];   // (B,M,5)
  char* ws = (char*)d_ws;
  // zero-init region [0, 282688): scalars, bpi, h1/h2 (packed u64), h3 (u32)
  double* lossL  = (double*)(ws + 0);
  double* lossCp = (double*)(ws + 8);
  double* lossCn = (double*)(ws + 16);
  unsigned int* ticket = (unsigned int*)(ws + 24);
  unsigned int* numpos = (unsigned int*)(ws + 32);            // [8]
  unsigned long long* bpi = (unsigned long long*)(ws + 64);   // [512]
  unsigned long long* h1 = (unsigned long long*)(ws + 4160);  // [8*2048]
  unsigned long long* h2 = (unsigned long long*)(ws + 135232);// [8*2048]
  unsigned int* h3 = (unsigned int*)(ws + 266304);            // [8*1024]
  const size_t ZINIT = 299072;
  unsigned char* matchOut = (unsigned char*)(ws + ZINIT);     // [B*A] u8
  unsigned int* ceBits = (unsigned int*)(ws + ZINIT + 1048576); // [B*A]
  // total ws use ~5.5 MB

  hipMemsetAsync(d_ws, 0, ZINIT, stream);
  k_match<<<dim3(64, 8), 512, 0, stream>>>(anchors, targets, matchOut, bpi);
  k_main<<<dim3(32, 8), 256, 0, stream>>>(loc, confp, anchors, targets, bpi,
                                          matchOut, ceBits, h1, lossL, lossCp,
                                          numpos);
  k_sel2<<<dim3(32, 8), 256, 0, stream>>>(ceBits, h1, h2, numpos);
  k_sel3<<<dim3(32, 8), 256, 0, stream>>>(ceBits, h1, h2, h3, numpos);
  k_final<<<8, 256, 0, stream>>>(h1, h2, h3, numpos, lossL, lossCp,
                                 lossCn, ticket, (float*)d_out);
}